// Round 17
// baseline (130.504 us; speedup 1.0000x reference)
//
#include <hip/hip_runtime.h>

#define NN 128
#define CC_ 16
#define HH 32
#define WW 32
#define DD 4096   // 16*16*16 pooled features per sample
#define ND (NN*DD)

typedef float v2f __attribute__((ext_vector_type(2)));

// c = sqrt(0.5*log2(e)); folded into the means so the per-term exponent is
// exp2(-(q*q)).
#define MU_SCALE 0.8493218002880191f

// ---------------------------------------------------------------------------
// Kernel 1: fused 2x2 avg-pool. FLOAT4-interleaved output:
//   wmv[n*DD+d] = {MU_SCALE*ma, MU_SCALE*mb, va, vb}
// Thread 0 zeroes d_out (poisoned 0xAA before every launch).
// ---------------------------------------------------------------------------
__global__ __launch_bounds__(256) void pool_kernel(
    const float* __restrict__ mu_a, const float* __restrict__ lv_a,
    const float* __restrict__ mu_b, const float* __restrict__ lv_b,
    float4* __restrict__ wmv, float* __restrict__ out)
{
    int t = blockIdx.x * 256 + threadIdx.x;
    if (t == 0) out[0] = 0.0f;

    int wo = t & 15;
    int ho = (t >> 4) & 15;
    int c  = (t >> 8) & 15;
    int n  = t >> 12;

    int base = ((n * CC_ + c) * HH + 2 * ho) * WW + 2 * wo;

    float2 a0 = *(const float2*)(mu_a + base);
    float2 a1 = *(const float2*)(mu_a + base + WW);
    float2 la0 = *(const float2*)(lv_a + base);
    float2 la1 = *(const float2*)(lv_a + base + WW);
    float2 b0 = *(const float2*)(mu_b + base);
    float2 b1 = *(const float2*)(mu_b + base + WW);
    float2 lb0 = *(const float2*)(lv_b + base);
    float2 lb1 = *(const float2*)(lv_b + base + WW);

    const float ms = 0.25f * MU_SCALE;
    float ma_v = ms * (a0.x + a0.y + a1.x + a1.y);
    float mb_v = ms * (b0.x + b0.y + b1.x + b1.y);
    float va_v = 0.0625f * (__expf(la0.x) + __expf(la0.y) + __expf(la1.x) + __expf(la1.y));
    float vb_v = 0.0625f * (__expf(lb0.x) + __expf(lb0.y) + __expf(lb1.x) + __expf(lb1.y));

    wmv[t] = make_float4(ma_v, mb_v, va_v, vb_v);
}

// ---------------------------------------------------------------------------
// Kernel 2: R16 structure (balanced units, 2 d-columns/thread, 12 chains)
// + R17: poly exp2 on the pk pipe, cutting trans instrs 4->2 per group.
// Converged model (R13/R15/R16 all ~104 cy/SIMD/group): wave64 trans ~25 cy,
// so 4 trans = 100 cy IS the measured plateau. Removing 2 exp from trans
// (50 cy) for ~12 full-rate VALU ops (~24 issue-cy, overlapped) drops the
// floor to ~55-65 cy/group. R14's poly failed at 6 chains/VGPR32; R16's 12
// chains at 4 waves/SIMD is the ILP this needs.
// ---------------------------------------------------------------------------
__device__ __forceinline__ v2f exp2_poly(v2f y)   // y <= 0, returns 2^y
{
    float n0 = __builtin_rintf(y.x);              // v_rndne_f32 (full rate)
    float n1 = __builtin_rintf(y.y);
    v2f f = y - (v2f){n0, n1};                    // pk_add, f in [-0.5, 0.5]
    const float c1 = 0.6931471805599453f;         // ln2 series
    const float c2 = 0.2402265069591007f;
    const float c3 = 0.0555041086648216f;
    const float c4 = 0.0096181291076285f;
    const float c5 = 0.0013333558146428f;
    v2f p = (v2f){c5, c5};
    p = p * f + (v2f){c4, c4};                    // 5x pk_fma
    p = p * f + (v2f){c3, c3};
    p = p * f + (v2f){c2, c2};
    p = p * f + (v2f){c1, c1};
    p = p * f + (v2f){1.0f, 1.0f};
    v2f e;
    e.x = __builtin_amdgcn_ldexpf(p.x, (int)n0);  // v_cvt_i32 + v_ldexp (full rate)
    e.y = __builtin_amdgcn_ldexpf(p.y, (int)n1);
    return e;
}

__device__ __forceinline__ void pair_group(
    v2f& acc, v2f mi, v2f mj, v2f vi, v2f vj)
{
    v2f dd = mi - mj;          // pk
    v2f s  = vi + vj;          // pk
    v2f r;
    r.x = __builtin_amdgcn_rsqf(s.x);   // the only remaining trans
    r.y = __builtin_amdgcn_rsqf(s.y);
    v2f q  = dd * r;           // pk
    v2f y  = q * (-q);         // pk (neg modifier)
    v2f e  = exp2_poly(y);
    acc += e * r;              // pk_fma
}

__device__ __forceinline__ void pair_group_w(
    v2f& acc, v2f w, v2f mi, v2f mj, v2f vi, v2f vj)
{
    v2f dd = mi - mj;
    v2f s  = vi + vj;
    v2f r;
    r.x = __builtin_amdgcn_rsqf(s.x);
    r.y = __builtin_amdgcn_rsqf(s.y);
    v2f q  = dd * r;
    v2f y  = q * (-q);
    v2f e  = exp2_poly(y);
    v2f er = e * r;
    acc += w * er;
}

// Rows and accumulators are [slot][p], slot = d-column 0/1.
__device__ __forceinline__ void run_range2(
    int jlo, int jhi, int i0, int d0, int d1,
    const float4* __restrict__ wmv,
    v2f acc_aa[2][2], v2f acc_bb[2][2], v2f acc_ab[2][2],
    const v2f pma[2][2], const v2f pmb[2][2],
    const v2f pva[2][2], const v2f pvb[2][2])
{
    const int below_end = min(jhi, i0);
    const int band_lo   = max(jlo, i0);
    const int band_hi   = min(jhi, i0 + 4);
    const int above_lo  = max(jlo, i0 + 4);

    // --- below diagonal: full aa + bb + ab (12 groups/j) ---
#pragma unroll 2
    for (int j = jlo; j < below_end; ++j) {
        float4 jr0 = wmv[j * DD + d0];
        float4 jr1 = wmv[j * DD + d1];
#pragma unroll
        for (int s = 0; s < 2; ++s) {
            float4 jr = s ? jr1 : jr0;
            v2f jma2 = (v2f){jr.x, jr.x};
            v2f jmb2 = (v2f){jr.y, jr.y};
            v2f jva2 = (v2f){jr.z, jr.z};
            v2f jvb2 = (v2f){jr.w, jr.w};
#pragma unroll
            for (int p = 0; p < 2; ++p) {
                pair_group(acc_aa[s][p], pma[s][p], jma2, pva[s][p], jva2);
                pair_group(acc_bb[s][p], pmb[s][p], jmb2, pvb[s][p], jvb2);
                pair_group(acc_ab[s][p], pma[s][p], jmb2, pva[s][p], jvb2);
            }
        }
    }

    // --- diagonal band (<=4 iters): per-row half-weights {1, .5, 0} ---
    for (int j = band_lo; j < band_hi; ++j) {
        float4 jr0 = wmv[j * DD + d0];
        float4 jr1 = wmv[j * DD + d1];
        v2f w[2];
#pragma unroll
        for (int p = 0; p < 2; ++p) {
            int r0 = i0 + 2 * p, r1 = r0 + 1;
            w[p].x = (j < r0) ? 1.0f : (j == r0 ? 0.5f : 0.0f);
            w[p].y = (j < r1) ? 1.0f : (j == r1 ? 0.5f : 0.0f);
        }
#pragma unroll
        for (int s = 0; s < 2; ++s) {
            float4 jr = s ? jr1 : jr0;
            v2f jma2 = (v2f){jr.x, jr.x};
            v2f jmb2 = (v2f){jr.y, jr.y};
            v2f jva2 = (v2f){jr.z, jr.z};
            v2f jvb2 = (v2f){jr.w, jr.w};
#pragma unroll
            for (int p = 0; p < 2; ++p) {
                pair_group_w(acc_aa[s][p], w[p], pma[s][p], jma2, pva[s][p], jva2);
                pair_group_w(acc_bb[s][p], w[p], pmb[s][p], jmb2, pvb[s][p], jvb2);
                pair_group(acc_ab[s][p], pma[s][p], jmb2, pva[s][p], jvb2);
            }
        }
    }

    // --- above diagonal: ab only (4 groups/j) ---
#pragma unroll 2
    for (int j = above_lo; j < jhi; ++j) {
        float4 jr0 = wmv[j * DD + d0];
        float4 jr1 = wmv[j * DD + d1];
#pragma unroll
        for (int s = 0; s < 2; ++s) {
            float4 jr = s ? jr1 : jr0;
            v2f jmb2 = (v2f){jr.y, jr.y};
            v2f jvb2 = (v2f){jr.w, jr.w};
#pragma unroll
            for (int p = 0; p < 2; ++p) {
                pair_group(acc_ab[s][p], pma[s][p], jmb2, pva[s][p], jvb2);
            }
        }
    }
}

// Load a tile's rows for both d-columns and run one (tile, chunk) unit.
__device__ __forceinline__ void process_unit2(
    int tile, int chunk, int d0, int d1, const float4* __restrict__ wmv,
    v2f acc_aa[2][2], v2f acc_bb[2][2], v2f acc_ab[2][2])
{
    const int i0 = tile * 4;
    v2f pma[2][2], pmb[2][2], pva[2][2], pvb[2][2];
#pragma unroll
    for (int s = 0; s < 2; ++s) {
        int d = s ? d1 : d0;
#pragma unroll
        for (int p = 0; p < 2; ++p) {
            float4 r0 = wmv[(i0 + 2 * p) * DD + d];
            float4 r1 = wmv[(i0 + 2 * p + 1) * DD + d];
            pma[s][p] = (v2f){r0.x, r1.x};
            pmb[s][p] = (v2f){r0.y, r1.y};
            pva[s][p] = (v2f){r0.z, r1.z};
            pvb[s][p] = (v2f){r0.w, r1.w};
        }
    }
    run_range2(chunk * 16, chunk * 16 + 16, i0, d0, d1, wmv,
               acc_aa, acc_bb, acc_ab, pma, pmb, pva, pvb);
}

// --- unit enumerations (wave-uniform, scalar) ---
// heavy tiles 16..31 (g=tile>>2 in 4..7), below-chunks c<g: 88 units
__device__ __forceinline__ uint2 heavy_below(int k) {
    int tile, c;
    if (k < 16)      { tile = 16 + (k >> 2);            c = k & 3; }
    else if (k < 36) { int kk = k - 16; tile = 20 + kk / 5; c = kk % 5; }
    else if (k < 60) { int kk = k - 36; tile = 24 + kk / 6; c = kk % 6; }
    else             { int kk = k - 60; tile = 28 + kk / 7; c = kk % 7; }
    return make_uint2(tile, c);
}
// light tiles 0..15 (g in 0..3), above-chunks c>g: 88 units
__device__ __forceinline__ uint2 light_above(int k) {
    int tile, c;
    if (k < 28)      { tile = k / 7;                    c = 1 + k % 7; }
    else if (k < 52) { int kk = k - 28; tile = 4 + kk / 6;  c = 2 + kk % 6; }
    else if (k < 72) { int kk = k - 52; tile = 8 + kk / 5;  c = 3 + kk % 5; }
    else             { int kk = k - 72; tile = 12 + (kk >> 2); c = 4 + (kk & 3); }
    return make_uint2(tile, c);
}
// light tiles, below-chunks c<g: 24 units
__device__ __forceinline__ uint2 light_below(int k) {
    int tile, c;
    if (k < 4)       { tile = 4 + k;                    c = 0; }
    else if (k < 12) { int kk = k - 4;  tile = 8 + (kk >> 1);  c = kk & 1; }
    else             { int kk = k - 12; tile = 12 + kk / 3; c = kk % 3; }
    return make_uint2(tile, c);
}
// heavy tiles, above-chunks c>g: 24 units
__device__ __forceinline__ uint2 heavy_above(int k) {
    int tile, c;
    if (k < 12)      { tile = 16 + k / 3;               c = 5 + k % 3; }
    else if (k < 20) { int kk = k - 12; tile = 20 + (kk >> 1); c = 6 + (kk & 1); }
    else             { tile = 24 + (k - 20);            c = 7; }
    return make_uint2(tile, c);
}

__global__ __launch_bounds__(256) void pair_kernel(
    const float4* __restrict__ wmv, float* __restrict__ out)
{
    const int d0 = blockIdx.x * 256 + threadIdx.x;   // 0..2047
    const int d1 = d0 + 2048;                        // 2048..4095
    const int y  = blockIdx.y;

    uint2 A, B;
    if (y < 88)       { A = heavy_below(y);       B = light_above(y); }
    else if (y < 112) { A = light_below(y - 88);  B = heavy_above(y - 88); }
    else              { int k = y - 112;
                        A = make_uint2(k, k >> 2);
                        B = make_uint2(31 - k, (31 - k) >> 2); }

    v2f acc_aa[2][2] = {{(v2f){0.f,0.f},(v2f){0.f,0.f}},{(v2f){0.f,0.f},(v2f){0.f,0.f}}};
    v2f acc_bb[2][2] = {{(v2f){0.f,0.f},(v2f){0.f,0.f}},{(v2f){0.f,0.f},(v2f){0.f,0.f}}};
    v2f acc_ab[2][2] = {{(v2f){0.f,0.f},(v2f){0.f,0.f}},{(v2f){0.f,0.f},(v2f){0.f,0.f}}};

    process_unit2((int)A.x, (int)A.y, d0, d1, wmv, acc_aa, acc_bb, acc_ab);
    process_unit2((int)B.x, (int)B.y, d0, d1, wmv, acc_aa, acc_bb, acc_ab);

    // vaa + vbb - 2 vab = 2 * (half_aa + half_bb - half_ab)
    v2f aa = (acc_aa[0][0] + acc_aa[0][1]) + (acc_aa[1][0] + acc_aa[1][1]);
    v2f bb = (acc_bb[0][0] + acc_bb[0][1]) + (acc_bb[1][0] + acc_bb[1][1]);
    v2f ab = (acc_ab[0][0] + acc_ab[0][1]) + (acc_ab[1][0] + acc_ab[1][1]);
    float part = 2.0f * ((aa.x + aa.y) + (bb.x + bb.y) - (ab.x + ab.y));

    // wave (64-lane) shuffle reduction
#pragma unroll
    for (int off = 32; off > 0; off >>= 1)
        part += __shfl_down(part, off, 64);

    __shared__ float wsum[4];
    int lane = threadIdx.x & 63;
    int wv_  = threadIdx.x >> 6;
    if (lane == 0) wsum[wv_] = part;
    __syncthreads();
    if (threadIdx.x == 0) {
        float s = wsum[0] + wsum[1] + wsum[2] + wsum[3];
        atomicAdd(out, s);
    }
}

extern "C" void kernel_launch(void* const* d_in, const int* in_sizes, int n_in,
                              void* d_out, int out_size, void* d_ws, size_t ws_size,
                              hipStream_t stream) {
    const float* mu_a = (const float*)d_in[0];
    const float* lv_a = (const float*)d_in[1];
    const float* mu_b = (const float*)d_in[2];
    const float* lv_b = (const float*)d_in[3];
    float* out  = (float*)d_out;
    float4* wmv = (float4*)d_ws;           // ND float4 = 8 MB

    pool_kernel<<<dim3(ND / 256), 256, 0, stream>>>(mu_a, lv_a, mu_b, lv_b, wmv, out);
    pair_kernel<<<dim3(DD / 512, 128), 256, 0, stream>>>(wmv, out);
}

// Round 18
// 111.875 us; speedup vs baseline: 1.1665x; 1.1665x over previous
//
#include <hip/hip_runtime.h>

#define NN 128
#define CC_ 16
#define HH 32
#define WW 32
#define DD 4096   // 16*16*16 pooled features per sample
#define ND (NN*DD)

typedef float v2f __attribute__((ext_vector_type(2)));

// c = sqrt(0.5*log2(e)); folded into the means so the per-term exponent is
// exp2(-(q*q)) with the negate absorbed by the v_exp input modifier.
#define MU_SCALE 0.8493218002880191f

// ---------------------------------------------------------------------------
// Kernel 1: fused 2x2 avg-pool. FLOAT4-interleaved output:
//   wmv[n*DD+d] = {MU_SCALE*ma, MU_SCALE*mb, va, vb}
// Thread 0 zeroes d_out (poisoned 0xAA before every launch).
// At HBM roofline: 32 MB read + 8 MB write ≈ 6 µs.
// ---------------------------------------------------------------------------
__global__ __launch_bounds__(256) void pool_kernel(
    const float* __restrict__ mu_a, const float* __restrict__ lv_a,
    const float* __restrict__ mu_b, const float* __restrict__ lv_b,
    float4* __restrict__ wmv, float* __restrict__ out)
{
    int t = blockIdx.x * 256 + threadIdx.x;
    if (t == 0) out[0] = 0.0f;

    int wo = t & 15;
    int ho = (t >> 4) & 15;
    int c  = (t >> 8) & 15;
    int n  = t >> 12;

    int base = ((n * CC_ + c) * HH + 2 * ho) * WW + 2 * wo;

    float2 a0 = *(const float2*)(mu_a + base);
    float2 a1 = *(const float2*)(mu_a + base + WW);
    float2 la0 = *(const float2*)(lv_a + base);
    float2 la1 = *(const float2*)(lv_a + base + WW);
    float2 b0 = *(const float2*)(mu_b + base);
    float2 b1 = *(const float2*)(mu_b + base + WW);
    float2 lb0 = *(const float2*)(lv_b + base);
    float2 lb1 = *(const float2*)(lv_b + base + WW);

    const float ms = 0.25f * MU_SCALE;
    float ma_v = ms * (a0.x + a0.y + a1.x + a1.y);
    float mb_v = ms * (b0.x + b0.y + b1.x + b1.y);
    float va_v = 0.0625f * (__expf(la0.x) + __expf(la0.y) + __expf(la1.x) + __expf(la1.y));
    float vb_v = 0.0625f * (__expf(lb0.x) + __expf(lb0.y) + __expf(lb1.x) + __expf(lb1.y));

    wmv[t] = make_float4(ma_v, mb_v, va_v, vb_v);
}

// ---------------------------------------------------------------------------
// Kernel 2: triangle-symmetric pair sums, exact uniform balance (R13 — the
// session's best). AT THE TRANS ROOFLINE: 4 transcendentals per v2f-group
// (2 rsq + 2 exp2) x 1.05M wave-groups / 1024 SIMDs x ~25 cy = ~43 us; all
// structural variants (R6/R13/R15/R16) measure 103-104 cy/group. Poly-exp2
// conversions (R14/R17) regressed both times; trans unit is the hard floor.
// ---------------------------------------------------------------------------
__device__ __forceinline__ void pair_group(
    v2f& acc, v2f mi, v2f mj, v2f vi, v2f vj)
{
    v2f dd = mi - mj;          // v_pk_add
    v2f s  = vi + vj;          // v_pk_add
    v2f r;
    r.x = __builtin_amdgcn_rsqf(s.x);
    r.y = __builtin_amdgcn_rsqf(s.y);
    v2f q  = dd * r;           // v_pk_mul
    v2f qq = q * q;            // v_pk_mul
    v2f e;
    e.x = __builtin_amdgcn_exp2f(-qq.x);
    e.y = __builtin_amdgcn_exp2f(-qq.y);
    acc += e * r;              // v_pk_fma
}

__device__ __forceinline__ void pair_group_w(
    v2f& acc, v2f w, v2f mi, v2f mj, v2f vi, v2f vj)
{
    v2f dd = mi - mj;
    v2f s  = vi + vj;
    v2f r;
    r.x = __builtin_amdgcn_rsqf(s.x);
    r.y = __builtin_amdgcn_rsqf(s.y);
    v2f q  = dd * r;
    v2f qq = q * q;
    v2f e;
    e.x = __builtin_amdgcn_exp2f(-qq.x);
    e.y = __builtin_amdgcn_exp2f(-qq.y);
    v2f er = e * r;
    acc += w * er;
}

// Process j in [jlo, jhi) against rows i0..i0+3 (3-range triangle split).
__device__ __forceinline__ void run_range(
    int jlo, int jhi, int i0, int d,
    const float4* __restrict__ wmv,
    v2f& acc_aa, v2f& acc_bb, v2f& acc_ab,
    const v2f pma[2], const v2f pmb[2], const v2f pva[2], const v2f pvb[2])
{
    const int below_end = min(jhi, i0);
    const int band_lo   = max(jlo, i0);
    const int band_hi   = min(jhi, i0 + 4);
    const int above_lo  = max(jlo, i0 + 4);

    // --- below diagonal: full aa + bb + ab ---
#pragma unroll 2
    for (int j = jlo; j < below_end; ++j) {
        float4 jr = wmv[j * DD + d];           // one dwordx4
        v2f jma2 = (v2f){jr.x, jr.x};
        v2f jmb2 = (v2f){jr.y, jr.y};
        v2f jva2 = (v2f){jr.z, jr.z};
        v2f jvb2 = (v2f){jr.w, jr.w};
#pragma unroll
        for (int p = 0; p < 2; ++p) {
            pair_group(acc_aa, pma[p], jma2, pva[p], jva2);
            pair_group(acc_bb, pmb[p], jmb2, pvb[p], jvb2);
            pair_group(acc_ab, pma[p], jmb2, pva[p], jvb2);
        }
    }

    // --- diagonal band (<=4 iters): per-row half-weights {1, .5, 0} ---
    for (int j = band_lo; j < band_hi; ++j) {
        float4 jr = wmv[j * DD + d];
        v2f jma2 = (v2f){jr.x, jr.x};
        v2f jmb2 = (v2f){jr.y, jr.y};
        v2f jva2 = (v2f){jr.z, jr.z};
        v2f jvb2 = (v2f){jr.w, jr.w};
        v2f w[2];
#pragma unroll
        for (int p = 0; p < 2; ++p) {
            int r0 = i0 + 2 * p, r1 = r0 + 1;
            w[p].x = (j < r0) ? 1.0f : (j == r0 ? 0.5f : 0.0f);
            w[p].y = (j < r1) ? 1.0f : (j == r1 ? 0.5f : 0.0f);
        }
#pragma unroll
        for (int p = 0; p < 2; ++p) {
            pair_group_w(acc_aa, w[p], pma[p], jma2, pva[p], jva2);
            pair_group_w(acc_bb, w[p], pmb[p], jmb2, pvb[p], jvb2);
            pair_group(acc_ab, pma[p], jmb2, pva[p], jvb2);
        }
    }

    // --- above diagonal: ab only ---
#pragma unroll 2
    for (int j = above_lo; j < jhi; ++j) {
        float4 jr = wmv[j * DD + d];
        v2f jmb2 = (v2f){jr.y, jr.y};
        v2f jvb2 = (v2f){jr.w, jr.w};
#pragma unroll
        for (int p = 0; p < 2; ++p) {
            pair_group(acc_ab, pma[p], jmb2, pva[p], jvb2);
        }
    }
}

// Load a tile's 4 rows and run one (tile, chunk) unit.
__device__ __forceinline__ void process_unit(
    int tile, int chunk, int d, const float4* __restrict__ wmv,
    v2f& acc_aa, v2f& acc_bb, v2f& acc_ab)
{
    const int i0 = tile * 4;
    v2f pma[2], pmb[2], pva[2], pvb[2];
#pragma unroll
    for (int p = 0; p < 2; ++p) {
        float4 r0 = wmv[(i0 + 2 * p) * DD + d];
        float4 r1 = wmv[(i0 + 2 * p + 1) * DD + d];
        pma[p] = (v2f){r0.x, r1.x};
        pmb[p] = (v2f){r0.y, r1.y};
        pva[p] = (v2f){r0.z, r1.z};
        pvb[p] = (v2f){r0.w, r1.w};
    }
    run_range(chunk * 16, chunk * 16 + 16, i0, d, wmv,
              acc_aa, acc_bb, acc_ab, pma, pmb, pva, pvb);
}

// --- unit enumerations (wave-uniform, scalar) ---
// heavy tiles 16..31 (g=tile>>2 in 4..7), below-chunks c<g: 88 units
__device__ __forceinline__ uint2 heavy_below(int k) {
    int tile, c;
    if (k < 16)      { tile = 16 + (k >> 2);            c = k & 3; }
    else if (k < 36) { int kk = k - 16; tile = 20 + kk / 5; c = kk % 5; }
    else if (k < 60) { int kk = k - 36; tile = 24 + kk / 6; c = kk % 6; }
    else             { int kk = k - 60; tile = 28 + kk / 7; c = kk % 7; }
    return make_uint2(tile, c);
}
// light tiles 0..15 (g in 0..3), above-chunks c>g: 88 units
__device__ __forceinline__ uint2 light_above(int k) {
    int tile, c;
    if (k < 28)      { tile = k / 7;                    c = 1 + k % 7; }
    else if (k < 52) { int kk = k - 28; tile = 4 + kk / 6;  c = 2 + kk % 6; }
    else if (k < 72) { int kk = k - 52; tile = 8 + kk / 5;  c = 3 + kk % 5; }
    else             { int kk = k - 72; tile = 12 + (kk >> 2); c = 4 + (kk & 3); }
    return make_uint2(tile, c);
}
// light tiles, below-chunks c<g: 24 units
__device__ __forceinline__ uint2 light_below(int k) {
    int tile, c;
    if (k < 4)       { tile = 4 + k;                    c = 0; }
    else if (k < 12) { int kk = k - 4;  tile = 8 + (kk >> 1);  c = kk & 1; }
    else             { int kk = k - 12; tile = 12 + kk / 3; c = kk % 3; }
    return make_uint2(tile, c);
}
// heavy tiles, above-chunks c>g: 24 units
__device__ __forceinline__ uint2 heavy_above(int k) {
    int tile, c;
    if (k < 12)      { tile = 16 + k / 3;               c = 5 + k % 3; }
    else if (k < 20) { int kk = k - 12; tile = 20 + (kk >> 1); c = 6 + (kk & 1); }
    else             { tile = 24 + (k - 20);            c = 7; }
    return make_uint2(tile, c);
}

__global__ __launch_bounds__(256) void pair_kernel(
    const float4* __restrict__ wmv, float* __restrict__ out)
{
    const int d = blockIdx.x * 256 + threadIdx.x;
    const int y = blockIdx.y;

    uint2 A, B;
    if (y < 88)       { A = heavy_below(y);       B = light_above(y); }
    else if (y < 112) { A = light_below(y - 88);  B = heavy_above(y - 88); }
    else              { int k = y - 112;
                        A = make_uint2(k, k >> 2);
                        B = make_uint2(31 - k, (31 - k) >> 2); }

    v2f acc_aa = (v2f){0.0f, 0.0f};
    v2f acc_bb = (v2f){0.0f, 0.0f};
    v2f acc_ab = (v2f){0.0f, 0.0f};

    process_unit((int)A.x, (int)A.y, d, wmv, acc_aa, acc_bb, acc_ab);
    process_unit((int)B.x, (int)B.y, d, wmv, acc_aa, acc_bb, acc_ab);

    // vaa + vbb - 2 vab = 2 * (half_aa + half_bb - half_ab)
    float part = 2.0f * ((acc_aa.x + acc_aa.y) + (acc_bb.x + acc_bb.y)
                       - (acc_ab.x + acc_ab.y));

    // wave (64-lane) shuffle reduction
#pragma unroll
    for (int off = 32; off > 0; off >>= 1)
        part += __shfl_down(part, off, 64);

    __shared__ float wsum[4];
    int lane = threadIdx.x & 63;
    int wv_  = threadIdx.x >> 6;
    if (lane == 0) wsum[wv_] = part;
    __syncthreads();
    if (threadIdx.x == 0) {
        float s = wsum[0] + wsum[1] + wsum[2] + wsum[3];
        atomicAdd(out, s);
    }
}

extern "C" void kernel_launch(void* const* d_in, const int* in_sizes, int n_in,
                              void* d_out, int out_size, void* d_ws, size_t ws_size,
                              hipStream_t stream) {
    const float* mu_a = (const float*)d_in[0];
    const float* lv_a = (const float*)d_in[1];
    const float* mu_b = (const float*)d_in[2];
    const float* lv_b = (const float*)d_in[3];
    float* out  = (float*)d_out;
    float4* wmv = (float4*)d_ws;           // ND float4 = 8 MB

    pool_kernel<<<dim3(ND / 256), 256, 0, stream>>>(mu_a, lv_a, mu_b, lv_b, wmv, out);
    pair_kernel<<<dim3(DD / 256, 128), 256, 0, stream>>>(wmv, out);
}